// Round 9
// baseline (147.699 us; speedup 1.0000x reference)
//
#include <hip/hip_runtime.h>
#include <hip/hip_bf16.h>

#define T_TOK 4096
#define D_IN  2048
#define HS    128
#define CKV   16     // 64-wide KV tiles per attention chunk (r8: was 8)
#define NCH   4      // ceil(64 / CKV)
#define NSLOT 160    // sum_q ceil((q+1)/16)

typedef unsigned short u16;
typedef __attribute__((ext_vector_type(8))) __bf16 bf16x8;
typedef __attribute__((ext_vector_type(4))) float f32x4;
typedef __attribute__((ext_vector_type(4))) unsigned short us4;
typedef __attribute__((ext_vector_type(8))) unsigned short us8;

#define GLOBAL_AS __attribute__((address_space(1)))
#define LDS_AS    __attribute__((address_space(3)))

__device__ __forceinline__ void async_ld16(const void* g, void* l) {
  __builtin_amdgcn_global_load_lds((GLOBAL_AS void*)(void*)g, (LDS_AS void*)l, 16, 0, 0);
}

__device__ __forceinline__ u16 f2bf(float v) {
  return __builtin_bit_cast(u16, __float2bfloat16(v));
}

// ---------------------------------------------------------------------------
// fp32-vs-bf16 autodetect on a buffer head: even u16s of fp32 data are raw
// low-mantissa bits -> ~25% have "exponent" field >= 0xBF; genuine bf16
// N(0,s) has none. Returns wave-uniform flag via LDS broadcast.
// ---------------------------------------------------------------------------
__device__ __forceinline__ bool detect_f32(const u16* in, int tid, int* sflag) {
  if (tid < 64) {
    int cnt = 0;
#pragma unroll
    for (int j = 0; j < 8; j++) {
      u16 v = in[(tid * 8 + j) * 2];
      cnt += (((v >> 7) & 0xFF) >= 0xBF) ? 1 : 0;
    }
#pragma unroll
    for (int off = 1; off < 64; off <<= 1) cnt += __shfl_xor(cnt, off);
    if (tid == 0) *sflag = (cnt > 8) ? 1 : 0;
  }
  __syncthreads();
  return (*sflag != 0);
}

// ---------------------------------------------------------------------------
// Weight normalizer: all three matrices, 128 blocks each; converts fp32->bf16
// (or copies bf16). mat0/blk0 publishes the dtype flag for the epilogue.
// (Lessons: no x pre-convert (r0); no fused last-arriver combine (r2);
// 32-wide attn tiles double per-step overhead (r6); partial-machinery bytes
// are the attn lever (r7: CKV 4->8 = -5.2us).)
// ---------------------------------------------------------------------------
__global__ __launch_bounds__(256) void conv3_kernel(
    const u16* __restrict__ w0, const u16* __restrict__ w1,
    const u16* __restrict__ w2, u16* __restrict__ o0,
    u16* __restrict__ o1, u16* __restrict__ o2, int* __restrict__ flag) {
  __shared__ int sflag;
  const int mat = blockIdx.x >> 7;
  const int blk = blockIdx.x & 127;
  const u16* in = (mat == 0) ? w0 : ((mat == 1) ? w1 : w2);
  u16* out = (mat == 0) ? o0 : ((mat == 1) ? o1 : o2);
  const int tid = threadIdx.x;
  const bool isf32 = detect_f32(in, tid, &sflag);
  if (tid == 0 && mat == 0 && blk == 0) *flag = isf32 ? 1 : 0;
  const size_t base = ((size_t)blk * 256 + tid) * 8;
  if (isf32) {
    const float* f = (const float*)in;
    us4 a, b;
#pragma unroll
    for (int j = 0; j < 4; j++) a[j] = f2bf(f[base + j]);
#pragma unroll
    for (int j = 0; j < 4; j++) b[j] = f2bf(f[base + 4 + j]);
    *(us4*)(out + base) = a;
    *(us4*)(out + base + 4) = b;
  } else {
    *(us8*)(out + base) = *(const us8*)(in + base);
  }
}

// ---------------------------------------------------------------------------
// QKV projection v7 (round-5 anchor, unchanged): BM=16, grid linear 768, mat
// fast axis (x L2/L3 reuse). 2-deep register pipeline at 36 KB LDS.
// ---------------------------------------------------------------------------
__global__ __launch_bounds__(256, 3) void qkv_kernel(
    const u16* __restrict__ x, const u16* __restrict__ Wq,
    const u16* __restrict__ Wk, const u16* __restrict__ Wv,
    u16* __restrict__ Q, u16* __restrict__ K, u16* __restrict__ Vt)
{
  __shared__ __align__(16) u16 As[2][16 * 64];    // 2 x 2 KB
  __shared__ __align__(16) u16 Bs[2][128 * 64];   // 2 x 16 KB
  __shared__ int sflag;

  const int bid = blockIdx.x;
  const int mat = bid % 3;                 // fast axis: x-tile L2/L3 reuse
  const int mtile = bid / 3;
  const u16* W = (mat == 0) ? Wq : ((mat == 1) ? Wk : Wv);
  const int tid = threadIdx.x;
  const int wv = tid >> 6, lane = tid & 63, l15 = lane & 15, quad = lane >> 4;
  const int row0 = mtile * 16;

  const bool isf32 = detect_f32(x, tid, &sflag);

  f32x4 acc[2];
#pragma unroll
  for (int i = 0; i < 2; i++) acc[i] = (f32x4)0.0f;

  const u16* wp[4]; int boff[4];
#pragma unroll
  for (int j = 0; j < 4; j++) {
    int s = (wv * 4 + j) * 64 + lane;
    int n = s >> 3, c = (s & 7) ^ (n & 7);
    wp[j] = W + (size_t)n * D_IN + c * 8;
    boff[j] = s * 16;
  }
  const int ar = tid >> 3;
  const int ac = (tid & 7) ^ (ar & 7);

  auto loadB = [&](us8 (&d)[4], int k0) {
#pragma unroll
    for (int j = 0; j < 4; j++) d[j] = *(const us8*)(wp[j] + k0);
  };
  auto writeB = [&](const us8 (&s)[4], int buf) {
#pragma unroll
    for (int j = 0; j < 4; j++) *(us8*)((char*)Bs[buf] + boff[j]) = s[j];
  };
  auto compute = [&](int cur) {
#pragma unroll
    for (int kc = 0; kc < 2; kc++) {
      const int rA = l15;
      const int cl = kc * 4 + quad;
      bf16x8 a = *(const bf16x8*)((const char*)As[cur] + (rA * 8 + (cl ^ (rA & 7))) * 16);
#pragma unroll
      for (int nt = 0; nt < 2; nt++) {
        int n = wv * 32 + 16 * nt + l15;
        bf16x8 b = *(const bf16x8*)((const char*)Bs[cur] + (n * 8 + (cl ^ (n & 7))) * 16);
        acc[nt] = __builtin_amdgcn_mfma_f32_16x16x32_bf16(a, b, acc[nt], 0, 0, 0);
      }
    }
  };

  if (isf32) {
    const float* xf = (const float*)x + (size_t)(row0 + ar) * D_IN + ac * 8;
    f32x4 a00, a01, a10, a11, aI0, aI1;
    us8 pb0[4], pb1[4], bI[4];
    auto loadA = [&](f32x4& d0, f32x4& d1, int k0) {
      if (tid < 128) { d0 = *(const f32x4*)(xf + k0); d1 = *(const f32x4*)(xf + k0 + 4); }
    };
    auto writeA = [&](const f32x4& d0, const f32x4& d1, int buf) {
      if (tid < 128) {
        us8 t;
#pragma unroll
        for (int j = 0; j < 4; j++) { t[j] = f2bf(d0[j]); t[4 + j] = f2bf(d1[j]); }
        *(us8*)((char*)As[buf] + (size_t)tid * 16) = t;
      }
    };

    loadB(bI, 0);        loadA(aI0, aI1, 0);
    loadB(pb0, 64);      loadA(a00, a01, 64);
    loadB(pb1, 128);     loadA(a10, a11, 128);
    writeB(bI, 0);       writeA(aI0, aI1, 0);
    asm volatile("s_waitcnt lgkmcnt(0)" ::: "memory");
    __builtin_amdgcn_s_barrier();
    __builtin_amdgcn_sched_barrier(0);

    for (int kt2 = 0; kt2 < 16; kt2++) {
      const int kt = kt2 * 2;
      writeB(pb0, 1); writeA(a00, a01, 1);
      if (kt + 3 < 32) { loadB(pb0, (kt + 3) * 64); loadA(a00, a01, (kt + 3) * 64); }
      compute(0);
      asm volatile("s_waitcnt lgkmcnt(0)" ::: "memory");
      __builtin_amdgcn_s_barrier();
      __builtin_amdgcn_sched_barrier(0);
      if (kt + 2 < 32) { writeB(pb1, 0); writeA(a10, a11, 0); }
      if (kt + 4 < 32) { loadB(pb1, (kt + 4) * 64); loadA(a10, a11, (kt + 4) * 64); }
      compute(1);
      if (kt2 < 15) {
        asm volatile("s_waitcnt lgkmcnt(0)" ::: "memory");
        __builtin_amdgcn_s_barrier();
        __builtin_amdgcn_sched_barrier(0);
      }
    }
  } else {
    const u16* xp = x + (size_t)(row0 + ar) * D_IN + ac * 8;
    us8 qa0, qa1, qaI;
    us8 pb0[4], pb1[4], bI[4];
    auto loadA = [&](us8& d, int k0) { if (tid < 128) d = *(const us8*)(xp + k0); };
    auto writeA = [&](const us8& s, int buf) {
      if (tid < 128) *(us8*)((char*)As[buf] + (size_t)tid * 16) = s;
    };

    loadB(bI, 0);        loadA(qaI, 0);
    loadB(pb0, 64);      loadA(qa0, 64);
    loadB(pb1, 128);     loadA(qa1, 128);
    writeB(bI, 0);       writeA(qaI, 0);
    asm volatile("s_waitcnt lgkmcnt(0)" ::: "memory");
    __builtin_amdgcn_s_barrier();
    __builtin_amdgcn_sched_barrier(0);

    for (int kt2 = 0; kt2 < 16; kt2++) {
      const int kt = kt2 * 2;
      writeB(pb0, 1); writeA(qa0, 1);
      if (kt + 3 < 32) { loadB(pb0, (kt + 3) * 64); loadA(qa0, (kt + 3) * 64); }
      compute(0);
      asm volatile("s_waitcnt lgkmcnt(0)" ::: "memory");
      __builtin_amdgcn_s_barrier();
      __builtin_amdgcn_sched_barrier(0);
      if (kt + 2 < 32) { writeB(pb1, 0); writeA(qa1, 0); }
      if (kt + 4 < 32) { loadB(pb1, (kt + 4) * 64); loadA(qa1, (kt + 4) * 64); }
      compute(1);
      if (kt2 < 15) {
        asm volatile("s_waitcnt lgkmcnt(0)" ::: "memory");
        __builtin_amdgcn_s_barrier();
        __builtin_amdgcn_sched_barrier(0);
      }
    }
  }

  if (mat < 2) {
    u16* out = (mat == 0) ? Q : K;
#pragma unroll
    for (int nt = 0; nt < 2; nt++)
#pragma unroll
      for (int r = 0; r < 4; r++) {
        int m = row0 + quad * 4 + r;
        int n = wv * 32 + 16 * nt + l15;
        out[(size_t)m * HS + n] = f2bf(acc[nt][r]);
      }
  } else {
#pragma unroll
    for (int nt = 0; nt < 2; nt++) {
      int n = wv * 32 + 16 * nt + l15;
      int mb = row0 + quad * 4;
      us4 pk;
#pragma unroll
      for (int r = 0; r < 4; r++) pk[r] = f2bf(acc[nt][r]);
      *(us4*)(Vt + (size_t)n * T_TOK + mb) = pk;
    }
  }
}

// ---------------------------------------------------------------------------
// Split-KV flash attention (64-wide tiles, CKV=16). grid (64 qtiles, 4
// chunks); block (qtile,ch) handles KV tiles [16ch, min(16ch+15, qtile)].
// r8: CKV 8->16 cuts slots 288->160 (Opart 9.4->5.2 MB each way); 160
// active blocks <= 256 CUs -> all co-resident from t=0, span ~= CKV=8's
// (which ran 2 blocks/CU serially). Continues the r7 bytes-lever.
// Dense slot: slot(q,ch) = 64ch - 8ch(ch-1) + (q - 16ch)   (max 159).
// T5 setprio + T13 defer-max kept (r3-verified safe).
// ---------------------------------------------------------------------------
__global__ __launch_bounds__(256, 2) void attn_split_kernel(
    const u16* __restrict__ Q, const u16* __restrict__ Kg,
    const u16* __restrict__ Vt, float* __restrict__ Opart,
    float* __restrict__ mstat, float* __restrict__ lstat)
{
  __shared__ __align__(16) u16 Ks[2][64 * 128];   // 2 x 16 KB
  __shared__ __align__(16) u16 Vs[2][128 * 64];   // 2 x 16 KB
  __shared__ __align__(16) u16 Ps[4 * 16 * 64];   // 8 KB (per-wave P)

  const int qtile = 63 - (int)blockIdx.x;         // heavy blocks first
  const int ch = blockIdx.y;
  if (16 * ch > qtile) return;
  const int t0 = 16 * ch;
  const int nsteps = min(CKV, qtile + 1 - t0);
  const int q0 = qtile * 64;
  const int slot = 64 * ch - 8 * ch * (ch - 1) + (qtile - 16 * ch);

  const int tid = threadIdx.x;
  const int wv = tid >> 6, lane = tid & 63, l15 = lane & 15, quad = lane >> 4;

  // Q A-frags: A[m=l15][k=quad*8+j]
  bf16x8 qf[4];
#pragma unroll
  for (int kc = 0; kc < 4; kc++)
    qf[kc] = *(const bf16x8*)(Q + (size_t)(q0 + 16 * wv + l15) * HS + kc * 32 + quad * 8);

  f32x4 o[8];
#pragma unroll
  for (int i = 0; i < 8; i++) o[i] = (f32x4)0.0f;
  float mrun[4], lrun[4];
#pragma unroll
  for (int r = 0; r < 4; r++) { mrun[r] = -1e30f; lrun[r] = 0.0f; }

  const float sc = 0.12752761571239668f; // log2(e)/sqrt(128)

  auto stage = [&](int t, int buf) {
#pragma unroll
    for (int j = 0; j < 4; j++) {
      int s = (wv * 4 + j) * 64 + lane;
      int n = s >> 4, cs = s & 15, c = cs ^ (n & 7);
      async_ld16(Kg + (size_t)(t * 64 + n) * HS + c * 8,
                 (char*)Ks[buf] + (size_t)(wv * 4 + j) * 1024);
    }
#pragma unroll
    for (int j = 0; j < 4; j++) {
      int s = (wv * 4 + j) * 64 + lane;
      int vr = s >> 3, cs = s & 7, c = cs ^ (vr & 7);
      async_ld16(Vt + (size_t)vr * T_TOK + t * 64 + c * 8,
                 (char*)Vs[buf] + (size_t)(wv * 4 + j) * 1024);
    }
  };

  stage(t0, 0);
  for (int i = 0; i < nsteps; i++) {
    const int cur = i & 1;
    const int t = t0 + i;
    __syncthreads();                           // drains loads for buf cur
    if (i + 1 < nsteps) stage(t + 1, 1 - cur); // prefetch overlaps compute

    // S = Q K^T
    f32x4 sacc[4];
#pragma unroll
    for (int nt = 0; nt < 4; nt++) sacc[nt] = (f32x4)0.0f;
    __builtin_amdgcn_s_setprio(1);
#pragma unroll
    for (int kc = 0; kc < 4; kc++) {
      const int cl = kc * 4 + quad;
#pragma unroll
      for (int nt = 0; nt < 4; nt++) {
        int n = 16 * nt + l15;
        bf16x8 b = *(const bf16x8*)((const char*)Ks[cur] + (n * 16 + (cl ^ (n & 7))) * 16);
        sacc[nt] = __builtin_amdgcn_mfma_f32_16x16x32_bf16(qf[kc], b, sacc[nt], 0, 0, 0);
      }
    }
    __builtin_amdgcn_s_setprio(0);

    // scale into log2 domain + causal mask (diagonal tile only)
    float s2[4][4];
    const bool diag = (t == qtile);
#pragma unroll
    for (int nt = 0; nt < 4; nt++)
#pragma unroll
      for (int r = 0; r < 4; r++) {
        float v = sacc[nt][r] * sc;
        if (diag) {
          int qr = q0 + 16 * wv + quad * 4 + r;
          int kr = t * 64 + 16 * nt + l15;
          if (kr > qr) v = -1e30f;
        }
        s2[nt][r] = v;
      }

    // online softmax with defer-max; each row lives in one quad's 16 lanes
#pragma unroll
    for (int r = 0; r < 4; r++) {
      float tmax = fmaxf(fmaxf(s2[0][r], s2[1][r]), fmaxf(s2[2][r], s2[3][r]));
#pragma unroll
      for (int off = 1; off < 16; off <<= 1) tmax = fmaxf(tmax, __shfl_xor(tmax, off));
      if (tmax > mrun[r] + 8.0f) {           // rescale only on real growth
        float alpha = exp2f(mrun[r] - tmax);
#pragma unroll
        for (int c = 0; c < 8; c++) o[c][r] *= alpha;
        lrun[r] *= alpha;
        mrun[r] = tmax;
      }
    }
    float p[4][4];
#pragma unroll
    for (int r = 0; r < 4; r++) {
      float s = 0.0f;
#pragma unroll
      for (int nt = 0; nt < 4; nt++) { p[nt][r] = exp2f(s2[nt][r] - mrun[r]); s += p[nt][r]; }
#pragma unroll
      for (int off = 1; off < 16; off <<= 1) s += __shfl_xor(s, off);
      lrun[r] += s;
    }

    // P: C-layout -> per-wave LDS (no barrier: DS in-order, Ps wave-private)
    u16* Pw = Ps + wv * 1024;
#pragma unroll
    for (int nt = 0; nt < 4; nt++)
#pragma unroll
      for (int r = 0; r < 4; r++) {
        int row = quad * 4 + r;
        int col = nt * 16 + l15;
        int cc = col >> 3, wi = col & 7;
        Pw[(row * 8 + (cc ^ (row & 7))) * 8 + wi] = f2bf(p[nt][r]);
      }

    // O += P V
    __builtin_amdgcn_s_setprio(1);
#pragma unroll
    for (int kc = 0; kc < 2; kc++) {
      const int cl = kc * 4 + quad;
      bf16x8 a = *(const bf16x8*)((const char*)Pw + (l15 * 8 + (cl ^ (l15 & 7))) * 16);
#pragma unroll
      for (int c = 0; c < 8; c++) {
        int vr = 16 * c + l15;
        bf16x8 b = *(const bf16x8*)((const char*)Vs[cur] + (vr * 8 + (cl ^ (vr & 7))) * 16);
        o[c] = __builtin_amdgcn_mfma_f32_16x16x32_bf16(a, b, o[c], 0, 0, 0);
      }
    }
    __builtin_amdgcn_s_setprio(0);
  }

  // store fp32 partial O + stats
  float* po = Opart + (size_t)slot * 64 * 128;
#pragma unroll
  for (int c = 0; c < 8; c++)
#pragma unroll
    for (int r = 0; r < 4; r++) {
      int ml = 16 * wv + quad * 4 + r;
      po[ml * 128 + 16 * c + l15] = o[c][r];
    }
  if (l15 == 0) {
#pragma unroll
    for (int r = 0; r < 4; r++) {
      int ml = 16 * wv + quad * 4 + r;
      mstat[slot * 64 + ml] = mrun[r];
      lstat[slot * 64 + ml] = lrun[r];
    }
  }
}

// ---------------------------------------------------------------------------
// Combine partials. grid (64 qtiles, 4 col-blocks), 256 threads.
// Thread handles one row x 8 cols. Output dtype per detected flag.
// CKV=16 slot layout: base(ch) = 64ch - 8ch(ch-1), s = base + q - 16ch.
// ---------------------------------------------------------------------------
__global__ __launch_bounds__(256) void combine_kernel(
    const float* __restrict__ Opart, const float* __restrict__ mstat,
    const float* __restrict__ lstat, void* __restrict__ out_v,
    const int* __restrict__ dflag)
{
  const int q = blockIdx.x;
  const int cb = blockIdx.y;
  const int tid = threadIdx.x;
  const int row = tid >> 2;
  const int col = cb * 32 + (tid & 3) * 8;
  const int nch = (q + 16) / 16;   // ceil((q+1)/16)
  const bool of32 = (*dflag != 0);

  float M = -1e30f;
  {
    int base = 0;
    for (int c = 0; c < nch; c++) {
      int s = base + q - 16 * c;
      M = fmaxf(M, mstat[s * 64 + row]);
      base += 64 - 16 * c;
    }
  }
  float l = 0.0f;
  float acc[8];
#pragma unroll
  for (int j = 0; j < 8; j++) acc[j] = 0.0f;
  {
    int base = 0;
    for (int c = 0; c < nch; c++) {
      int s = base + q - 16 * c;
      float w = exp2f(mstat[s * 64 + row] - M);
      l += w * lstat[s * 64 + row];
      const float* op = Opart + ((size_t)s * 64 + row) * 128 + col;
      f32x4 a = *(const f32x4*)op;
      f32x4 b = *(const f32x4*)(op + 4);
#pragma unroll
      for (int j = 0; j < 4; j++) { acc[j] += w * a[j]; acc[4 + j] += w * b[j]; }
      base += 64 - 16 * c;
    }
  }
  const float inv = 1.0f / l;
  const size_t goff = (size_t)(q * 64 + row) * HS + col;
  if (of32) {
    float* out = (float*)out_v + goff;
    f32x4 r0, r1;
#pragma unroll
    for (int j = 0; j < 4; j++) { r0[j] = acc[j] * inv; r1[j] = acc[4 + j] * inv; }
    *(f32x4*)out = r0;
    *(f32x4*)(out + 4) = r1;
  } else {
    u16* out = (u16*)out_v + goff;
    us4 r0, r1;
#pragma unroll
    for (int j = 0; j < 4; j++) { r0[j] = f2bf(acc[j] * inv); r1[j] = f2bf(acc[4 + j] * inv); }
    *(us4*)out = r0;
    *(us4*)(out + 4) = r1;
  }
}

extern "C" void kernel_launch(void* const* d_in, const int* in_sizes, int n_in,
                              void* d_out, int out_size, void* d_ws, size_t ws_size,
                              hipStream_t stream) {
  const u16* x  = (const u16*)d_in[0];
  const u16* Wq = (const u16*)d_in[1];
  const u16* Wk = (const u16*)d_in[2];
  const u16* Wv = (const u16*)d_in[3];

  // ws layout (u16 units). Keep the 544-slot-sized region (only 160 used)
  // so downstream offsets are untouched.
  float* Opart = (float*)d_ws;                   // <=544 * 64*128 fp32
  float* mstat = Opart + (size_t)544 * 64 * 128;
  float* lstat = mstat + (size_t)544 * 64;

  u16* Wqb = (u16*)(lstat + (size_t)544 * 64);   // 3 x 128*2048 bf16
  u16* Wkb = Wqb + (size_t)HS * D_IN;
  u16* Wvb = Wkb + (size_t)HS * D_IN;
  u16* Q   = Wvb + (size_t)HS * D_IN;            // 4096*128 bf16 each
  u16* K   = Q   + (size_t)T_TOK * HS;
  u16* Vt  = K   + (size_t)T_TOK * HS;
  int* flag = (int*)(Vt + (size_t)T_TOK * HS);

  conv3_kernel<<<384, 256, 0, stream>>>(Wq, Wk, Wv, Wqb, Wkb, Wvb, flag);
  qkv_kernel<<<768, 256, 0, stream>>>(x, Wqb, Wkb, Wvb, Q, K, Vt);
  attn_split_kernel<<<dim3(64, NCH), 256, 0, stream>>>(Q, K, Vt, Opart, mstat, lstat);
  combine_kernel<<<dim3(64, 4), 256, 0, stream>>>(Opart, mstat, lstat, d_out, flag);
}

// Round 10
// 134.358 us; speedup vs baseline: 1.0993x; 1.0993x over previous
//
#include <hip/hip_runtime.h>
#include <hip/hip_bf16.h>

#define T_TOK 4096
#define D_IN  2048
#define HS    128
#define CKV   8      // 64-wide KV tiles per attention chunk (r8 optimum)
#define NCH   8      // ceil(64 / CKV)

typedef unsigned short u16;
typedef __attribute__((ext_vector_type(8))) __bf16 bf16x8;
typedef __attribute__((ext_vector_type(4))) float f32x4;
typedef __attribute__((ext_vector_type(4))) unsigned short us4;
typedef __attribute__((ext_vector_type(8))) unsigned short us8;

#define GLOBAL_AS __attribute__((address_space(1)))
#define LDS_AS    __attribute__((address_space(3)))

__device__ __forceinline__ void async_ld16(const void* g, void* l) {
  __builtin_amdgcn_global_load_lds((GLOBAL_AS void*)(void*)g, (LDS_AS void*)l, 16, 0, 0);
}

__device__ __forceinline__ u16 f2bf(float v) {
  return __builtin_bit_cast(u16, __float2bfloat16(v));
}

__device__ __forceinline__ float bf2f(u16 v) {
  return __builtin_bit_cast(float, (unsigned)v << 16);
}

// ---------------------------------------------------------------------------
// fp32-vs-bf16 autodetect on a buffer head: even u16s of fp32 data are raw
// low-mantissa bits -> ~25% have "exponent" field >= 0xBF; genuine bf16
// N(0,s) has none. Returns wave-uniform flag via LDS broadcast.
// ---------------------------------------------------------------------------
__device__ __forceinline__ bool detect_f32(const u16* in, int tid, int* sflag) {
  if (tid < 64) {
    int cnt = 0;
#pragma unroll
    for (int j = 0; j < 8; j++) {
      u16 v = in[(tid * 8 + j) * 2];
      cnt += (((v >> 7) & 0xFF) >= 0xBF) ? 1 : 0;
    }
#pragma unroll
    for (int off = 1; off < 64; off <<= 1) cnt += __shfl_xor(cnt, off);
    if (tid == 0) *sflag = (cnt > 8) ? 1 : 0;
  }
  __syncthreads();
  return (*sflag != 0);
}

// ---------------------------------------------------------------------------
// Weight normalizer: all three matrices, 128 blocks each; converts fp32->bf16
// (or copies bf16). mat0/blk0 publishes the dtype flag for the epilogue.
// (Lessons: no x pre-convert (r0); no fused last-arriver combine (r2);
// 32-wide attn tiles double per-step overhead (r6); CKV=8 is the TLP/bytes
// optimum (r7 win, r8 regression at CKV=16: 1 block/CU kills latency hiding).)
// ---------------------------------------------------------------------------
__global__ __launch_bounds__(256) void conv3_kernel(
    const u16* __restrict__ w0, const u16* __restrict__ w1,
    const u16* __restrict__ w2, u16* __restrict__ o0,
    u16* __restrict__ o1, u16* __restrict__ o2, int* __restrict__ flag) {
  __shared__ int sflag;
  const int mat = blockIdx.x >> 7;
  const int blk = blockIdx.x & 127;
  const u16* in = (mat == 0) ? w0 : ((mat == 1) ? w1 : w2);
  u16* out = (mat == 0) ? o0 : ((mat == 1) ? o1 : o2);
  const int tid = threadIdx.x;
  const bool isf32 = detect_f32(in, tid, &sflag);
  if (tid == 0 && mat == 0 && blk == 0) *flag = isf32 ? 1 : 0;
  const size_t base = ((size_t)blk * 256 + tid) * 8;
  if (isf32) {
    const float* f = (const float*)in;
    us4 a, b;
#pragma unroll
    for (int j = 0; j < 4; j++) a[j] = f2bf(f[base + j]);
#pragma unroll
    for (int j = 0; j < 4; j++) b[j] = f2bf(f[base + 4 + j]);
    *(us4*)(out + base) = a;
    *(us4*)(out + base + 4) = b;
  } else {
    *(us8*)(out + base) = *(const us8*)(in + base);
  }
}

// ---------------------------------------------------------------------------
// QKV projection v7 (round-5 anchor, unchanged): BM=16, grid linear 768, mat
// fast axis (x L2/L3 reuse). 2-deep register pipeline at 36 KB LDS.
// ---------------------------------------------------------------------------
__global__ __launch_bounds__(256, 3) void qkv_kernel(
    const u16* __restrict__ x, const u16* __restrict__ Wq,
    const u16* __restrict__ Wk, const u16* __restrict__ Wv,
    u16* __restrict__ Q, u16* __restrict__ K, u16* __restrict__ Vt)
{
  __shared__ __align__(16) u16 As[2][16 * 64];    // 2 x 2 KB
  __shared__ __align__(16) u16 Bs[2][128 * 64];   // 2 x 16 KB
  __shared__ int sflag;

  const int bid = blockIdx.x;
  const int mat = bid % 3;                 // fast axis: x-tile L2/L3 reuse
  const int mtile = bid / 3;
  const u16* W = (mat == 0) ? Wq : ((mat == 1) ? Wk : Wv);
  const int tid = threadIdx.x;
  const int wv = tid >> 6, lane = tid & 63, l15 = lane & 15, quad = lane >> 4;
  const int row0 = mtile * 16;

  const bool isf32 = detect_f32(x, tid, &sflag);

  f32x4 acc[2];
#pragma unroll
  for (int i = 0; i < 2; i++) acc[i] = (f32x4)0.0f;

  const u16* wp[4]; int boff[4];
#pragma unroll
  for (int j = 0; j < 4; j++) {
    int s = (wv * 4 + j) * 64 + lane;
    int n = s >> 3, c = (s & 7) ^ (n & 7);
    wp[j] = W + (size_t)n * D_IN + c * 8;
    boff[j] = s * 16;
  }
  const int ar = tid >> 3;
  const int ac = (tid & 7) ^ (ar & 7);

  auto loadB = [&](us8 (&d)[4], int k0) {
#pragma unroll
    for (int j = 0; j < 4; j++) d[j] = *(const us8*)(wp[j] + k0);
  };
  auto writeB = [&](const us8 (&s)[4], int buf) {
#pragma unroll
    for (int j = 0; j < 4; j++) *(us8*)((char*)Bs[buf] + boff[j]) = s[j];
  };
  auto compute = [&](int cur) {
#pragma unroll
    for (int kc = 0; kc < 2; kc++) {
      const int rA = l15;
      const int cl = kc * 4 + quad;
      bf16x8 a = *(const bf16x8*)((const char*)As[cur] + (rA * 8 + (cl ^ (rA & 7))) * 16);
#pragma unroll
      for (int nt = 0; nt < 2; nt++) {
        int n = wv * 32 + 16 * nt + l15;
        bf16x8 b = *(const bf16x8*)((const char*)Bs[cur] + (n * 8 + (cl ^ (n & 7))) * 16);
        acc[nt] = __builtin_amdgcn_mfma_f32_16x16x32_bf16(a, b, acc[nt], 0, 0, 0);
      }
    }
  };

  if (isf32) {
    const float* xf = (const float*)x + (size_t)(row0 + ar) * D_IN + ac * 8;
    f32x4 a00, a01, a10, a11, aI0, aI1;
    us8 pb0[4], pb1[4], bI[4];
    auto loadA = [&](f32x4& d0, f32x4& d1, int k0) {
      if (tid < 128) { d0 = *(const f32x4*)(xf + k0); d1 = *(const f32x4*)(xf + k0 + 4); }
    };
    auto writeA = [&](const f32x4& d0, const f32x4& d1, int buf) {
      if (tid < 128) {
        us8 t;
#pragma unroll
        for (int j = 0; j < 4; j++) { t[j] = f2bf(d0[j]); t[4 + j] = f2bf(d1[j]); }
        *(us8*)((char*)As[buf] + (size_t)tid * 16) = t;
      }
    };

    loadB(bI, 0);        loadA(aI0, aI1, 0);
    loadB(pb0, 64);      loadA(a00, a01, 64);
    loadB(pb1, 128);     loadA(a10, a11, 128);
    writeB(bI, 0);       writeA(aI0, aI1, 0);
    asm volatile("s_waitcnt lgkmcnt(0)" ::: "memory");
    __builtin_amdgcn_s_barrier();
    __builtin_amdgcn_sched_barrier(0);

    for (int kt2 = 0; kt2 < 16; kt2++) {
      const int kt = kt2 * 2;
      writeB(pb0, 1); writeA(a00, a01, 1);
      if (kt + 3 < 32) { loadB(pb0, (kt + 3) * 64); loadA(a00, a01, (kt + 3) * 64); }
      compute(0);
      asm volatile("s_waitcnt lgkmcnt(0)" ::: "memory");
      __builtin_amdgcn_s_barrier();
      __builtin_amdgcn_sched_barrier(0);
      if (kt + 2 < 32) { writeB(pb1, 0); writeA(a10, a11, 0); }
      if (kt + 4 < 32) { loadB(pb1, (kt + 4) * 64); loadA(a10, a11, (kt + 4) * 64); }
      compute(1);
      if (kt2 < 15) {
        asm volatile("s_waitcnt lgkmcnt(0)" ::: "memory");
        __builtin_amdgcn_s_barrier();
        __builtin_amdgcn_sched_barrier(0);
      }
    }
  } else {
    const u16* xp = x + (size_t)(row0 + ar) * D_IN + ac * 8;
    us8 qa0, qa1, qaI;
    us8 pb0[4], pb1[4], bI[4];
    auto loadA = [&](us8& d, int k0) { if (tid < 128) d = *(const us8*)(xp + k0); };
    auto writeA = [&](const us8& s, int buf) {
      if (tid < 128) *(us8*)((char*)As[buf] + (size_t)tid * 16) = s;
    };

    loadB(bI, 0);        loadA(qaI, 0);
    loadB(pb0, 64);      loadA(qa0, 64);
    loadB(pb1, 128);     loadA(qa1, 128);
    writeB(bI, 0);       writeA(qaI, 0);
    asm volatile("s_waitcnt lgkmcnt(0)" ::: "memory");
    __builtin_amdgcn_s_barrier();
    __builtin_amdgcn_sched_barrier(0);

    for (int kt2 = 0; kt2 < 16; kt2++) {
      const int kt = kt2 * 2;
      writeB(pb0, 1); writeA(qa0, 1);
      if (kt + 3 < 32) { loadB(pb0, (kt + 3) * 64); loadA(qa0, (kt + 3) * 64); }
      compute(0);
      asm volatile("s_waitcnt lgkmcnt(0)" ::: "memory");
      __builtin_amdgcn_s_barrier();
      __builtin_amdgcn_sched_barrier(0);
      if (kt + 2 < 32) { writeB(pb1, 0); writeA(qa1, 0); }
      if (kt + 4 < 32) { loadB(pb1, (kt + 4) * 64); loadA(qa1, (kt + 4) * 64); }
      compute(1);
      if (kt2 < 15) {
        asm volatile("s_waitcnt lgkmcnt(0)" ::: "memory");
        __builtin_amdgcn_s_barrier();
        __builtin_amdgcn_sched_barrier(0);
      }
    }
  }

  if (mat < 2) {
    u16* out = (mat == 0) ? Q : K;
#pragma unroll
    for (int nt = 0; nt < 2; nt++)
#pragma unroll
      for (int r = 0; r < 4; r++) {
        int m = row0 + quad * 4 + r;
        int n = wv * 32 + 16 * nt + l15;
        out[(size_t)m * HS + n] = f2bf(acc[nt][r]);
      }
  } else {
#pragma unroll
    for (int nt = 0; nt < 2; nt++) {
      int n = wv * 32 + 16 * nt + l15;
      int mb = row0 + quad * 4;
      us4 pk;
#pragma unroll
      for (int r = 0; r < 4; r++) pk[r] = f2bf(acc[nt][r]);
      *(us4*)(Vt + (size_t)n * T_TOK + mb) = pk;
    }
  }
}

// ---------------------------------------------------------------------------
// Split-KV flash attention (64-wide tiles, CKV=8 — r7 optimum restored).
// grid (64 qtiles, 8 chunks); block (qtile,ch) covers KV tiles
// [8ch, min(8ch+7, qtile)]. 288 blocks at 2/CU co-residency (r8 lesson:
// CKV=16's 160 blocks = 1/CU lost all latency hiding, +12us).
// r9 change: partial O stored in BF16 (m/l stay fp32) — Opart traffic
// 9.4+9.4 -> 4.7+4.7 MB at ~0.3us/MB marginal (r7-measured).
// Dense slot: slot(q,ch) = 64ch - 4ch(ch-1) + (q - 8ch).
// T5 setprio + T13 defer-max kept (r3-verified safe).
// ---------------------------------------------------------------------------
__global__ __launch_bounds__(256, 2) void attn_split_kernel(
    const u16* __restrict__ Q, const u16* __restrict__ Kg,
    const u16* __restrict__ Vt, u16* __restrict__ Opart,
    float* __restrict__ mstat, float* __restrict__ lstat)
{
  __shared__ __align__(16) u16 Ks[2][64 * 128];   // 2 x 16 KB
  __shared__ __align__(16) u16 Vs[2][128 * 64];   // 2 x 16 KB
  __shared__ __align__(16) u16 Ps[4 * 16 * 64];   // 8 KB (per-wave P)

  const int qtile = 63 - (int)blockIdx.x;         // heavy blocks first
  const int ch = blockIdx.y;
  if (8 * ch > qtile) return;
  const int t0 = 8 * ch;
  const int nsteps = min(CKV, qtile + 1 - t0);
  const int q0 = qtile * 64;
  const int slot = 64 * ch - 4 * ch * (ch - 1) + (qtile - 8 * ch);

  const int tid = threadIdx.x;
  const int wv = tid >> 6, lane = tid & 63, l15 = lane & 15, quad = lane >> 4;

  // Q A-frags: A[m=l15][k=quad*8+j]
  bf16x8 qf[4];
#pragma unroll
  for (int kc = 0; kc < 4; kc++)
    qf[kc] = *(const bf16x8*)(Q + (size_t)(q0 + 16 * wv + l15) * HS + kc * 32 + quad * 8);

  f32x4 o[8];
#pragma unroll
  for (int i = 0; i < 8; i++) o[i] = (f32x4)0.0f;
  float mrun[4], lrun[4];
#pragma unroll
  for (int r = 0; r < 4; r++) { mrun[r] = -1e30f; lrun[r] = 0.0f; }

  const float sc = 0.12752761571239668f; // log2(e)/sqrt(128)

  auto stage = [&](int t, int buf) {
#pragma unroll
    for (int j = 0; j < 4; j++) {
      int s = (wv * 4 + j) * 64 + lane;
      int n = s >> 4, cs = s & 15, c = cs ^ (n & 7);
      async_ld16(Kg + (size_t)(t * 64 + n) * HS + c * 8,
                 (char*)Ks[buf] + (size_t)(wv * 4 + j) * 1024);
    }
#pragma unroll
    for (int j = 0; j < 4; j++) {
      int s = (wv * 4 + j) * 64 + lane;
      int vr = s >> 3, cs = s & 7, c = cs ^ (vr & 7);
      async_ld16(Vt + (size_t)vr * T_TOK + t * 64 + c * 8,
                 (char*)Vs[buf] + (size_t)(wv * 4 + j) * 1024);
    }
  };

  stage(t0, 0);
  for (int i = 0; i < nsteps; i++) {
    const int cur = i & 1;
    const int t = t0 + i;
    __syncthreads();                           // drains loads for buf cur
    if (i + 1 < nsteps) stage(t + 1, 1 - cur); // prefetch overlaps compute

    // S = Q K^T
    f32x4 sacc[4];
#pragma unroll
    for (int nt = 0; nt < 4; nt++) sacc[nt] = (f32x4)0.0f;
    __builtin_amdgcn_s_setprio(1);
#pragma unroll
    for (int kc = 0; kc < 4; kc++) {
      const int cl = kc * 4 + quad;
#pragma unroll
      for (int nt = 0; nt < 4; nt++) {
        int n = 16 * nt + l15;
        bf16x8 b = *(const bf16x8*)((const char*)Ks[cur] + (n * 16 + (cl ^ (n & 7))) * 16);
        sacc[nt] = __builtin_amdgcn_mfma_f32_16x16x32_bf16(qf[kc], b, sacc[nt], 0, 0, 0);
      }
    }
    __builtin_amdgcn_s_setprio(0);

    // scale into log2 domain + causal mask (diagonal tile only)
    float s2[4][4];
    const bool diag = (t == qtile);
#pragma unroll
    for (int nt = 0; nt < 4; nt++)
#pragma unroll
      for (int r = 0; r < 4; r++) {
        float v = sacc[nt][r] * sc;
        if (diag) {
          int qr = q0 + 16 * wv + quad * 4 + r;
          int kr = t * 64 + 16 * nt + l15;
          if (kr > qr) v = -1e30f;
        }
        s2[nt][r] = v;
      }

    // online softmax with defer-max; each row lives in one quad's 16 lanes
#pragma unroll
    for (int r = 0; r < 4; r++) {
      float tmax = fmaxf(fmaxf(s2[0][r], s2[1][r]), fmaxf(s2[2][r], s2[3][r]));
#pragma unroll
      for (int off = 1; off < 16; off <<= 1) tmax = fmaxf(tmax, __shfl_xor(tmax, off));
      if (tmax > mrun[r] + 8.0f) {           // rescale only on real growth
        float alpha = exp2f(mrun[r] - tmax);
#pragma unroll
        for (int c = 0; c < 8; c++) o[c][r] *= alpha;
        lrun[r] *= alpha;
        mrun[r] = tmax;
      }
    }
    float p[4][4];
#pragma unroll
    for (int r = 0; r < 4; r++) {
      float s = 0.0f;
#pragma unroll
      for (int nt = 0; nt < 4; nt++) { p[nt][r] = exp2f(s2[nt][r] - mrun[r]); s += p[nt][r]; }
#pragma unroll
      for (int off = 1; off < 16; off <<= 1) s += __shfl_xor(s, off);
      lrun[r] += s;
    }

    // P: C-layout -> per-wave LDS (no barrier: DS in-order, Ps wave-private)
    u16* Pw = Ps + wv * 1024;
#pragma unroll
    for (int nt = 0; nt < 4; nt++)
#pragma unroll
      for (int r = 0; r < 4; r++) {
        int row = quad * 4 + r;
        int col = nt * 16 + l15;
        int cc = col >> 3, wi = col & 7;
        Pw[(row * 8 + (cc ^ (row & 7))) * 8 + wi] = f2bf(p[nt][r]);
      }

    // O += P V
    __builtin_amdgcn_s_setprio(1);
#pragma unroll
    for (int kc = 0; kc < 2; kc++) {
      const int cl = kc * 4 + quad;
      bf16x8 a = *(const bf16x8*)((const char*)Pw + (l15 * 8 + (cl ^ (l15 & 7))) * 16);
#pragma unroll
      for (int c = 0; c < 8; c++) {
        int vr = 16 * c + l15;
        bf16x8 b = *(const bf16x8*)((const char*)Vs[cur] + (vr * 8 + (cl ^ (vr & 7))) * 16);
        o[c] = __builtin_amdgcn_mfma_f32_16x16x32_bf16(a, b, o[c], 0, 0, 0);
      }
    }
    __builtin_amdgcn_s_setprio(0);
  }

  // store BF16 partial O + fp32 stats
  u16* po = Opart + (size_t)slot * 64 * 128;
#pragma unroll
  for (int c = 0; c < 8; c++)
#pragma unroll
    for (int r = 0; r < 4; r++) {
      int ml = 16 * wv + quad * 4 + r;
      po[ml * 128 + 16 * c + l15] = f2bf(o[c][r]);
    }
  if (l15 == 0) {
#pragma unroll
    for (int r = 0; r < 4; r++) {
      int ml = 16 * wv + quad * 4 + r;
      mstat[slot * 64 + ml] = mrun[r];
      lstat[slot * 64 + ml] = lrun[r];
    }
  }
}

// ---------------------------------------------------------------------------
// Combine partials. grid (64 qtiles, 4 col-blocks), 256 threads.
// Thread handles one row x 8 cols. Partials are BF16 (r9); stats fp32.
// CKV=8 slot layout: base(ch) = 64ch - 4ch(ch-1), s = base + q - 8ch.
// ---------------------------------------------------------------------------
__global__ __launch_bounds__(256) void combine_kernel(
    const u16* __restrict__ Opart, const float* __restrict__ mstat,
    const float* __restrict__ lstat, void* __restrict__ out_v,
    const int* __restrict__ dflag)
{
  const int q = blockIdx.x;
  const int cb = blockIdx.y;
  const int tid = threadIdx.x;
  const int row = tid >> 2;
  const int col = cb * 32 + (tid & 3) * 8;
  const int nch = (q + 8) / 8;   // ceil((q+1)/8)
  const bool of32 = (*dflag != 0);

  float M = -1e30f;
  {
    int base = 0;
    for (int c = 0; c < nch; c++) {
      int s = base + q - 8 * c;
      M = fmaxf(M, mstat[s * 64 + row]);
      base += 64 - 8 * c;
    }
  }
  float l = 0.0f;
  float acc[8];
#pragma unroll
  for (int j = 0; j < 8; j++) acc[j] = 0.0f;
  {
    int base = 0;
    for (int c = 0; c < nch; c++) {
      int s = base + q - 8 * c;
      float w = exp2f(mstat[s * 64 + row] - M);
      l += w * lstat[s * 64 + row];
      const u16* op = Opart + ((size_t)s * 64 + row) * 128 + col;
      us8 a = *(const us8*)op;
#pragma unroll
      for (int j = 0; j < 8; j++) acc[j] += w * bf2f(a[j]);
      base += 64 - 8 * c;
    }
  }
  const float inv = 1.0f / l;
  const size_t goff = (size_t)(q * 64 + row) * HS + col;
  if (of32) {
    float* out = (float*)out_v + goff;
    f32x4 r0, r1;
#pragma unroll
    for (int j = 0; j < 4; j++) { r0[j] = acc[j] * inv; r1[j] = acc[4 + j] * inv; }
    *(f32x4*)out = r0;
    *(f32x4*)(out + 4) = r1;
  } else {
    u16* out = (u16*)out_v + goff;
    us4 r0, r1;
#pragma unroll
    for (int j = 0; j < 4; j++) { r0[j] = f2bf(acc[j] * inv); r1[j] = f2bf(acc[4 + j] * inv); }
    *(us4*)out = r0;
    *(us4*)(out + 4) = r1;
  }
}

extern "C" void kernel_launch(void* const* d_in, const int* in_sizes, int n_in,
                              void* d_out, int out_size, void* d_ws, size_t ws_size,
                              hipStream_t stream) {
  const u16* x  = (const u16*)d_in[0];
  const u16* Wq = (const u16*)d_in[1];
  const u16* Wk = (const u16*)d_in[2];
  const u16* Wv = (const u16*)d_in[3];

  // ws layout. Opart region kept at its historical (fp32-sized) extent so
  // downstream offsets are untouched; bf16 partials use the first half.
  u16* Opart   = (u16*)d_ws;                     // 288 * 64*128 bf16 used
  float* mstat = (float*)d_ws + (size_t)544 * 64 * 128;
  float* lstat = mstat + (size_t)544 * 64;

  u16* Wqb = (u16*)(lstat + (size_t)544 * 64);   // 3 x 128*2048 bf16
  u16* Wkb = Wqb + (size_t)HS * D_IN;
  u16* Wvb = Wkb + (size_t)HS * D_IN;
  u16* Q   = Wvb + (size_t)HS * D_IN;            // 4096*128 bf16 each
  u16* K   = Q   + (size_t)T_TOK * HS;
  u16* Vt  = K   + (size_t)T_TOK * HS;
  int* flag = (int*)(Vt + (size_t)T_TOK * HS);

  conv3_kernel<<<384, 256, 0, stream>>>(Wq, Wk, Wv, Wqb, Wkb, Wvb, flag);
  qkv_kernel<<<768, 256, 0, stream>>>(x, Wqb, Wkb, Wvb, Q, K, Vt);
  attn_split_kernel<<<dim3(64, NCH), 256, 0, stream>>>(Q, K, Vt, Opart, mstat, lstat);
  combine_kernel<<<dim3(64, 4), 256, 0, stream>>>(Opart, mstat, lstat, d_out, flag);
}

// Round 11
// 127.603 us; speedup vs baseline: 1.1575x; 1.0529x over previous
//
#include <hip/hip_runtime.h>
#include <hip/hip_bf16.h>

#define T_TOK 4096
#define D_IN  2048
#define HS    128
#define CKV   8      // 64-wide KV tiles per attention chunk (r8 optimum)
#define NCH   8      // ceil(64 / CKV)

typedef unsigned short u16;
typedef __attribute__((ext_vector_type(8))) __bf16 bf16x8;
typedef __attribute__((ext_vector_type(4))) float f32x4;
typedef __attribute__((ext_vector_type(4))) unsigned short us4;
typedef __attribute__((ext_vector_type(8))) unsigned short us8;

#define GLOBAL_AS __attribute__((address_space(1)))
#define LDS_AS    __attribute__((address_space(3)))

__device__ __forceinline__ void async_ld16(const void* g, void* l) {
  __builtin_amdgcn_global_load_lds((GLOBAL_AS void*)(void*)g, (LDS_AS void*)l, 16, 0, 0);
}

__device__ __forceinline__ u16 f2bf(float v) {
  return __builtin_bit_cast(u16, __float2bfloat16(v));
}

__device__ __forceinline__ float bf2f(u16 v) {
  return __builtin_bit_cast(float, (unsigned)v << 16);
}

// ---------------------------------------------------------------------------
// fp32-vs-bf16 autodetect on a buffer head: even u16s of fp32 data are raw
// low-mantissa bits -> ~25% have "exponent" field >= 0xBF; genuine bf16
// N(0,s) has none. Returns wave-uniform flag via LDS broadcast.
// ---------------------------------------------------------------------------
__device__ __forceinline__ bool detect_f32(const u16* in, int tid, int* sflag) {
  if (tid < 64) {
    int cnt = 0;
#pragma unroll
    for (int j = 0; j < 8; j++) {
      u16 v = in[(tid * 8 + j) * 2];
      cnt += (((v >> 7) & 0xFF) >= 0xBF) ? 1 : 0;
    }
#pragma unroll
    for (int off = 1; off < 64; off <<= 1) cnt += __shfl_xor(cnt, off);
    if (tid == 0) *sflag = (cnt > 8) ? 1 : 0;
  }
  __syncthreads();
  return (*sflag != 0);
}

// ---------------------------------------------------------------------------
// Weight normalizer: all three matrices, 128 blocks each; converts fp32->bf16
// (or copies bf16). mat0/blk0 publishes the dtype flag for the epilogue.
// (Lessons: no x pre-convert (r0); no fused last-arriver combine (r2);
// 32-wide attn tiles double per-step overhead (r6); CKV=8 is the TLP/bytes
// optimum (r7/r8); bf16 partials OK (r9).)
// ---------------------------------------------------------------------------
__global__ __launch_bounds__(256) void conv3_kernel(
    const u16* __restrict__ w0, const u16* __restrict__ w1,
    const u16* __restrict__ w2, u16* __restrict__ o0,
    u16* __restrict__ o1, u16* __restrict__ o2, int* __restrict__ flag) {
  __shared__ int sflag;
  const int mat = blockIdx.x >> 7;
  const int blk = blockIdx.x & 127;
  const u16* in = (mat == 0) ? w0 : ((mat == 1) ? w1 : w2);
  u16* out = (mat == 0) ? o0 : ((mat == 1) ? o1 : o2);
  const int tid = threadIdx.x;
  const bool isf32 = detect_f32(in, tid, &sflag);
  if (tid == 0 && mat == 0 && blk == 0) *flag = isf32 ? 1 : 0;
  const size_t base = ((size_t)blk * 256 + tid) * 8;
  if (isf32) {
    const float* f = (const float*)in;
    us4 a, b;
#pragma unroll
    for (int j = 0; j < 4; j++) a[j] = f2bf(f[base + j]);
#pragma unroll
    for (int j = 0; j < 4; j++) b[j] = f2bf(f[base + 4 + j]);
    *(us4*)(out + base) = a;
    *(us4*)(out + base + 4) = b;
  } else {
    *(us8*)(out + base) = *(const us8*)(in + base);
  }
}

// ---------------------------------------------------------------------------
// QKV projection v7 (round-5 anchor, unchanged): BM=16, grid linear 768, mat
// fast axis (x L2/L3 reuse). 2-deep register pipeline at 36 KB LDS.
// ---------------------------------------------------------------------------
__global__ __launch_bounds__(256, 3) void qkv_kernel(
    const u16* __restrict__ x, const u16* __restrict__ Wq,
    const u16* __restrict__ Wk, const u16* __restrict__ Wv,
    u16* __restrict__ Q, u16* __restrict__ K, u16* __restrict__ Vt)
{
  __shared__ __align__(16) u16 As[2][16 * 64];    // 2 x 2 KB
  __shared__ __align__(16) u16 Bs[2][128 * 64];   // 2 x 16 KB
  __shared__ int sflag;

  const int bid = blockIdx.x;
  const int mat = bid % 3;                 // fast axis: x-tile L2/L3 reuse
  const int mtile = bid / 3;
  const u16* W = (mat == 0) ? Wq : ((mat == 1) ? Wk : Wv);
  const int tid = threadIdx.x;
  const int wv = tid >> 6, lane = tid & 63, l15 = lane & 15, quad = lane >> 4;
  const int row0 = mtile * 16;

  const bool isf32 = detect_f32(x, tid, &sflag);

  f32x4 acc[2];
#pragma unroll
  for (int i = 0; i < 2; i++) acc[i] = (f32x4)0.0f;

  const u16* wp[4]; int boff[4];
#pragma unroll
  for (int j = 0; j < 4; j++) {
    int s = (wv * 4 + j) * 64 + lane;
    int n = s >> 3, c = (s & 7) ^ (n & 7);
    wp[j] = W + (size_t)n * D_IN + c * 8;
    boff[j] = s * 16;
  }
  const int ar = tid >> 3;
  const int ac = (tid & 7) ^ (ar & 7);

  auto loadB = [&](us8 (&d)[4], int k0) {
#pragma unroll
    for (int j = 0; j < 4; j++) d[j] = *(const us8*)(wp[j] + k0);
  };
  auto writeB = [&](const us8 (&s)[4], int buf) {
#pragma unroll
    for (int j = 0; j < 4; j++) *(us8*)((char*)Bs[buf] + boff[j]) = s[j];
  };
  auto compute = [&](int cur) {
#pragma unroll
    for (int kc = 0; kc < 2; kc++) {
      const int rA = l15;
      const int cl = kc * 4 + quad;
      bf16x8 a = *(const bf16x8*)((const char*)As[cur] + (rA * 8 + (cl ^ (rA & 7))) * 16);
#pragma unroll
      for (int nt = 0; nt < 2; nt++) {
        int n = wv * 32 + 16 * nt + l15;
        bf16x8 b = *(const bf16x8*)((const char*)Bs[cur] + (n * 8 + (cl ^ (n & 7))) * 16);
        acc[nt] = __builtin_amdgcn_mfma_f32_16x16x32_bf16(a, b, acc[nt], 0, 0, 0);
      }
    }
  };

  if (isf32) {
    const float* xf = (const float*)x + (size_t)(row0 + ar) * D_IN + ac * 8;
    f32x4 a00, a01, a10, a11, aI0, aI1;
    us8 pb0[4], pb1[4], bI[4];
    auto loadA = [&](f32x4& d0, f32x4& d1, int k0) {
      if (tid < 128) { d0 = *(const f32x4*)(xf + k0); d1 = *(const f32x4*)(xf + k0 + 4); }
    };
    auto writeA = [&](const f32x4& d0, const f32x4& d1, int buf) {
      if (tid < 128) {
        us8 t;
#pragma unroll
        for (int j = 0; j < 4; j++) { t[j] = f2bf(d0[j]); t[4 + j] = f2bf(d1[j]); }
        *(us8*)((char*)As[buf] + (size_t)tid * 16) = t;
      }
    };

    loadB(bI, 0);        loadA(aI0, aI1, 0);
    loadB(pb0, 64);      loadA(a00, a01, 64);
    loadB(pb1, 128);     loadA(a10, a11, 128);
    writeB(bI, 0);       writeA(aI0, aI1, 0);
    asm volatile("s_waitcnt lgkmcnt(0)" ::: "memory");
    __builtin_amdgcn_s_barrier();
    __builtin_amdgcn_sched_barrier(0);

    for (int kt2 = 0; kt2 < 16; kt2++) {
      const int kt = kt2 * 2;
      writeB(pb0, 1); writeA(a00, a01, 1);
      if (kt + 3 < 32) { loadB(pb0, (kt + 3) * 64); loadA(a00, a01, (kt + 3) * 64); }
      compute(0);
      asm volatile("s_waitcnt lgkmcnt(0)" ::: "memory");
      __builtin_amdgcn_s_barrier();
      __builtin_amdgcn_sched_barrier(0);
      if (kt + 2 < 32) { writeB(pb1, 0); writeA(a10, a11, 0); }
      if (kt + 4 < 32) { loadB(pb1, (kt + 4) * 64); loadA(a10, a11, (kt + 4) * 64); }
      compute(1);
      if (kt2 < 15) {
        asm volatile("s_waitcnt lgkmcnt(0)" ::: "memory");
        __builtin_amdgcn_s_barrier();
        __builtin_amdgcn_sched_barrier(0);
      }
    }
  } else {
    const u16* xp = x + (size_t)(row0 + ar) * D_IN + ac * 8;
    us8 qa0, qa1, qaI;
    us8 pb0[4], pb1[4], bI[4];
    auto loadA = [&](us8& d, int k0) { if (tid < 128) d = *(const us8*)(xp + k0); };
    auto writeA = [&](const us8& s, int buf) {
      if (tid < 128) *(us8*)((char*)As[buf] + (size_t)tid * 16) = s;
    };

    loadB(bI, 0);        loadA(qaI, 0);
    loadB(pb0, 64);      loadA(qa0, 64);
    loadB(pb1, 128);     loadA(qa1, 128);
    writeB(bI, 0);       writeA(qaI, 0);
    asm volatile("s_waitcnt lgkmcnt(0)" ::: "memory");
    __builtin_amdgcn_s_barrier();
    __builtin_amdgcn_sched_barrier(0);

    for (int kt2 = 0; kt2 < 16; kt2++) {
      const int kt = kt2 * 2;
      writeB(pb0, 1); writeA(qa0, 1);
      if (kt + 3 < 32) { loadB(pb0, (kt + 3) * 64); loadA(qa0, (kt + 3) * 64); }
      compute(0);
      asm volatile("s_waitcnt lgkmcnt(0)" ::: "memory");
      __builtin_amdgcn_s_barrier();
      __builtin_amdgcn_sched_barrier(0);
      if (kt + 2 < 32) { writeB(pb1, 0); writeA(qa1, 0); }
      if (kt + 4 < 32) { loadB(pb1, (kt + 4) * 64); loadA(qa1, (kt + 4) * 64); }
      compute(1);
      if (kt2 < 15) {
        asm volatile("s_waitcnt lgkmcnt(0)" ::: "memory");
        __builtin_amdgcn_s_barrier();
        __builtin_amdgcn_sched_barrier(0);
      }
    }
  }

  if (mat < 2) {
    u16* out = (mat == 0) ? Q : K;
#pragma unroll
    for (int nt = 0; nt < 2; nt++)
#pragma unroll
      for (int r = 0; r < 4; r++) {
        int m = row0 + quad * 4 + r;
        int n = wv * 32 + 16 * nt + l15;
        out[(size_t)m * HS + n] = f2bf(acc[nt][r]);
      }
  } else {
#pragma unroll
    for (int nt = 0; nt < 2; nt++) {
      int n = wv * 32 + 16 * nt + l15;
      int mb = row0 + quad * 4;
      us4 pk;
#pragma unroll
      for (int r = 0; r < 4; r++) pk[r] = f2bf(acc[nt][r]);
      *(us4*)(Vt + (size_t)n * T_TOK + mb) = pk;
    }
  }
}

// ---------------------------------------------------------------------------
// Split-KV flash attention (64-wide tiles, CKV=8, bf16 partials — r9 best).
// r10 change: softmax cross-lane work removed from the common path.
//  (a) SUM reduce hoisted out of the step loop: lane-local lsum[r]
//      accumulates p; scaled by alpha at rescale events; ONE 4-shfl
//      reduce at the end (was 4 dependent shfl EVERY step).
//  (b) MAX reduce gated behind wave-wide __any(s2 > mrun+8): common path
//      (defer-max holds) = 16 lane-local cmps, zero cross-lane ops.
//      First step always trips (mrun=-1e30) -> mrun initialized; alpha =
//      exp2(-inf) = 0 harmlessly zeroes empty accumulators.
// Semantics identical to r9's defer-max (p <= 2^8, fp32 sums; only the
// summation order changes). Dense slot: slot(q,ch)=64ch-4ch(ch-1)+(q-8ch).
// ---------------------------------------------------------------------------
__global__ __launch_bounds__(256, 2) void attn_split_kernel(
    const u16* __restrict__ Q, const u16* __restrict__ Kg,
    const u16* __restrict__ Vt, u16* __restrict__ Opart,
    float* __restrict__ mstat, float* __restrict__ lstat)
{
  __shared__ __align__(16) u16 Ks[2][64 * 128];   // 2 x 16 KB
  __shared__ __align__(16) u16 Vs[2][128 * 64];   // 2 x 16 KB
  __shared__ __align__(16) u16 Ps[4 * 16 * 64];   // 8 KB (per-wave P)

  const int qtile = 63 - (int)blockIdx.x;         // heavy blocks first
  const int ch = blockIdx.y;
  if (8 * ch > qtile) return;
  const int t0 = 8 * ch;
  const int nsteps = min(CKV, qtile + 1 - t0);
  const int q0 = qtile * 64;
  const int slot = 64 * ch - 4 * ch * (ch - 1) + (qtile - 8 * ch);

  const int tid = threadIdx.x;
  const int wv = tid >> 6, lane = tid & 63, l15 = lane & 15, quad = lane >> 4;

  // Q A-frags: A[m=l15][k=quad*8+j]
  bf16x8 qf[4];
#pragma unroll
  for (int kc = 0; kc < 4; kc++)
    qf[kc] = *(const bf16x8*)(Q + (size_t)(q0 + 16 * wv + l15) * HS + kc * 32 + quad * 8);

  f32x4 o[8];
#pragma unroll
  for (int i = 0; i < 8; i++) o[i] = (f32x4)0.0f;
  float mrun[4], lsum[4];
#pragma unroll
  for (int r = 0; r < 4; r++) { mrun[r] = -1e30f; lsum[r] = 0.0f; }

  const float sc = 0.12752761571239668f; // log2(e)/sqrt(128)

  auto stage = [&](int t, int buf) {
#pragma unroll
    for (int j = 0; j < 4; j++) {
      int s = (wv * 4 + j) * 64 + lane;
      int n = s >> 4, cs = s & 15, c = cs ^ (n & 7);
      async_ld16(Kg + (size_t)(t * 64 + n) * HS + c * 8,
                 (char*)Ks[buf] + (size_t)(wv * 4 + j) * 1024);
    }
#pragma unroll
    for (int j = 0; j < 4; j++) {
      int s = (wv * 4 + j) * 64 + lane;
      int vr = s >> 3, cs = s & 7, c = cs ^ (vr & 7);
      async_ld16(Vt + (size_t)vr * T_TOK + t * 64 + c * 8,
                 (char*)Vs[buf] + (size_t)(wv * 4 + j) * 1024);
    }
  };

  stage(t0, 0);
  for (int i = 0; i < nsteps; i++) {
    const int cur = i & 1;
    const int t = t0 + i;
    __syncthreads();                           // drains loads for buf cur
    if (i + 1 < nsteps) stage(t + 1, 1 - cur); // prefetch overlaps compute

    // S = Q K^T
    f32x4 sacc[4];
#pragma unroll
    for (int nt = 0; nt < 4; nt++) sacc[nt] = (f32x4)0.0f;
    __builtin_amdgcn_s_setprio(1);
#pragma unroll
    for (int kc = 0; kc < 4; kc++) {
      const int cl = kc * 4 + quad;
#pragma unroll
      for (int nt = 0; nt < 4; nt++) {
        int n = 16 * nt + l15;
        bf16x8 b = *(const bf16x8*)((const char*)Ks[cur] + (n * 16 + (cl ^ (n & 7))) * 16);
        sacc[nt] = __builtin_amdgcn_mfma_f32_16x16x32_bf16(qf[kc], b, sacc[nt], 0, 0, 0);
      }
    }
    __builtin_amdgcn_s_setprio(0);

    // scale into log2 domain + causal mask (diagonal tile only)
    float s2[4][4];
    const bool diag = (t == qtile);
#pragma unroll
    for (int nt = 0; nt < 4; nt++)
#pragma unroll
      for (int r = 0; r < 4; r++) {
        float v = sacc[nt][r] * sc;
        if (diag) {
          int qr = q0 + 16 * wv + quad * 4 + r;
          int kr = t * 64 + 16 * nt + l15;
          if (kr > qr) v = -1e30f;
        }
        s2[nt][r] = v;
      }

    // gated online softmax (r10): common path = no cross-lane ops
    int pred = 0;
#pragma unroll
    for (int nt = 0; nt < 4; nt++)
#pragma unroll
      for (int r = 0; r < 4; r++) pred |= (s2[nt][r] > mrun[r] + 8.0f) ? 1 : 0;
    if (__any(pred)) {
#pragma unroll
      for (int r = 0; r < 4; r++) {
        float tmax = fmaxf(fmaxf(s2[0][r], s2[1][r]), fmaxf(s2[2][r], s2[3][r]));
#pragma unroll
        for (int off = 1; off < 16; off <<= 1) tmax = fmaxf(tmax, __shfl_xor(tmax, off));
        float mnew = fmaxf(mrun[r], tmax);
        float alpha = exp2f(mrun[r] - mnew);
#pragma unroll
        for (int c = 0; c < 8; c++) o[c][r] *= alpha;
        lsum[r] *= alpha;
        mrun[r] = mnew;
      }
    }
    float p[4][4];
#pragma unroll
    for (int r = 0; r < 4; r++)
#pragma unroll
      for (int nt = 0; nt < 4; nt++) {
        p[nt][r] = exp2f(s2[nt][r] - mrun[r]);
        lsum[r] += p[nt][r];
      }

    // P: C-layout -> per-wave LDS (no barrier: DS in-order, Ps wave-private)
    u16* Pw = Ps + wv * 1024;
#pragma unroll
    for (int nt = 0; nt < 4; nt++)
#pragma unroll
      for (int r = 0; r < 4; r++) {
        int row = quad * 4 + r;
        int col = nt * 16 + l15;
        int cc = col >> 3, wi = col & 7;
        Pw[(row * 8 + (cc ^ (row & 7))) * 8 + wi] = f2bf(p[nt][r]);
      }

    // O += P V
    __builtin_amdgcn_s_setprio(1);
#pragma unroll
    for (int kc = 0; kc < 2; kc++) {
      const int cl = kc * 4 + quad;
      bf16x8 a = *(const bf16x8*)((const char*)Pw + (l15 * 8 + (cl ^ (l15 & 7))) * 16);
#pragma unroll
      for (int c = 0; c < 8; c++) {
        int vr = 16 * c + l15;
        bf16x8 b = *(const bf16x8*)((const char*)Vs[cur] + (vr * 8 + (cl ^ (vr & 7))) * 16);
        o[c] = __builtin_amdgcn_mfma_f32_16x16x32_bf16(a, b, o[c], 0, 0, 0);
      }
    }
    __builtin_amdgcn_s_setprio(0);
  }

  // final cross-lane sum reduce (hoisted out of the loop, r10)
  float lrun[4];
#pragma unroll
  for (int r = 0; r < 4; r++) {
    float s = lsum[r];
#pragma unroll
    for (int off = 1; off < 16; off <<= 1) s += __shfl_xor(s, off);
    lrun[r] = s;
  }

  // store BF16 partial O + fp32 stats
  u16* po = Opart + (size_t)slot * 64 * 128;
#pragma unroll
  for (int c = 0; c < 8; c++)
#pragma unroll
    for (int r = 0; r < 4; r++) {
      int ml = 16 * wv + quad * 4 + r;
      po[ml * 128 + 16 * c + l15] = f2bf(o[c][r]);
    }
  if (l15 == 0) {
#pragma unroll
    for (int r = 0; r < 4; r++) {
      int ml = 16 * wv + quad * 4 + r;
      mstat[slot * 64 + ml] = mrun[r];
      lstat[slot * 64 + ml] = lrun[r];
    }
  }
}

// ---------------------------------------------------------------------------
// Combine partials. grid (64 qtiles, 4 col-blocks), 256 threads.
// Thread handles one row x 8 cols. Partials are BF16 (r9); stats fp32.
// CKV=8 slot layout: base(ch) = 64ch - 4ch(ch-1), s = base + q - 8ch.
// ---------------------------------------------------------------------------
__global__ __launch_bounds__(256) void combine_kernel(
    const u16* __restrict__ Opart, const float* __restrict__ mstat,
    const float* __restrict__ lstat, void* __restrict__ out_v,
    const int* __restrict__ dflag)
{
  const int q = blockIdx.x;
  const int cb = blockIdx.y;
  const int tid = threadIdx.x;
  const int row = tid >> 2;
  const int col = cb * 32 + (tid & 3) * 8;
  const int nch = (q + 8) / 8;   // ceil((q+1)/8)
  const bool of32 = (*dflag != 0);

  float M = -1e30f;
  {
    int base = 0;
    for (int c = 0; c < nch; c++) {
      int s = base + q - 8 * c;
      M = fmaxf(M, mstat[s * 64 + row]);
      base += 64 - 8 * c;
    }
  }
  float l = 0.0f;
  float acc[8];
#pragma unroll
  for (int j = 0; j < 8; j++) acc[j] = 0.0f;
  {
    int base = 0;
    for (int c = 0; c < nch; c++) {
      int s = base + q - 8 * c;
      float w = exp2f(mstat[s * 64 + row] - M);
      l += w * lstat[s * 64 + row];
      const u16* op = Opart + ((size_t)s * 64 + row) * 128 + col;
      us8 a = *(const us8*)op;
#pragma unroll
      for (int j = 0; j < 8; j++) acc[j] += w * bf2f(a[j]);
      base += 64 - 8 * c;
    }
  }
  const float inv = 1.0f / l;
  const size_t goff = (size_t)(q * 64 + row) * HS + col;
  if (of32) {
    float* out = (float*)out_v + goff;
    f32x4 r0, r1;
#pragma unroll
    for (int j = 0; j < 4; j++) { r0[j] = acc[j] * inv; r1[j] = acc[4 + j] * inv; }
    *(f32x4*)out = r0;
    *(f32x4*)(out + 4) = r1;
  } else {
    u16* out = (u16*)out_v + goff;
    us4 r0, r1;
#pragma unroll
    for (int j = 0; j < 4; j++) { r0[j] = f2bf(acc[j] * inv); r1[j] = f2bf(acc[4 + j] * inv); }
    *(us4*)out = r0;
    *(us4*)(out + 4) = r1;
  }
}

extern "C" void kernel_launch(void* const* d_in, const int* in_sizes, int n_in,
                              void* d_out, int out_size, void* d_ws, size_t ws_size,
                              hipStream_t stream) {
  const u16* x  = (const u16*)d_in[0];
  const u16* Wq = (const u16*)d_in[1];
  const u16* Wk = (const u16*)d_in[2];
  const u16* Wv = (const u16*)d_in[3];

  // ws layout. Opart region kept at its historical (fp32-sized) extent so
  // downstream offsets are untouched; bf16 partials use the first half.
  u16* Opart   = (u16*)d_ws;                     // 288 * 64*128 bf16 used
  float* mstat = (float*)d_ws + (size_t)544 * 64 * 128;
  float* lstat = mstat + (size_t)544 * 64;

  u16* Wqb = (u16*)(lstat + (size_t)544 * 64);   // 3 x 128*2048 bf16
  u16* Wkb = Wqb + (size_t)HS * D_IN;
  u16* Wvb = Wkb + (size_t)HS * D_IN;
  u16* Q   = Wvb + (size_t)HS * D_IN;            // 4096*128 bf16 each
  u16* K   = Q   + (size_t)T_TOK * HS;
  u16* Vt  = K   + (size_t)T_TOK * HS;
  int* flag = (int*)(Vt + (size_t)T_TOK * HS);

  conv3_kernel<<<384, 256, 0, stream>>>(Wq, Wk, Wv, Wqb, Wkb, Wvb, flag);
  qkv_kernel<<<768, 256, 0, stream>>>(x, Wqb, Wkb, Wvb, Q, K, Vt);
  attn_split_kernel<<<dim3(64, NCH), 256, 0, stream>>>(Q, K, Vt, Opart, mstat, lstat);
  combine_kernel<<<dim3(64, 4), 256, 0, stream>>>(Opart, mstat, lstat, d_out, flag);
}